// Round 2
// baseline (411.053 us; speedup 1.0000x reference)
//
#include <hip/hip_runtime.h>

#define BB 8
#define HH 64
#define WW 64
#define CC 128
#define FF 128

// ---------------------------------------------------------------------------
// Kernel 1: offset-predicting 3x3 'SAME' conv.
// grid = B*H blocks (one image row each), 256 threads (4 waves).
// Layout: px on lanes (conflict-free LDS reads), c split across waves and
// two staging phases (keeps static LDS under 64 KB). offset_w reads are
// wave-uniform -> scalar loads. Output: offs[B,H,W,18] fp32 in workspace.
// ---------------------------------------------------------------------------
__global__ __launch_bounds__(256)
void offsets_kernel(const float* __restrict__ x, const float* __restrict__ ow,
                    const float* __restrict__ ob, float* __restrict__ offs_out)
{
    // phase-staged x, transposed: [row 3][c_local 64][w+1 .. 66]  (50.7 KB)
    __shared__ __align__(16) float smem[3 * 64 * 66];

    const int blk  = blockIdx.x;          // 0..511
    const int b    = blk >> 6;
    const int h    = blk & 63;
    const int tid  = threadIdx.x;
    const int lane = tid & 63;            // px (column)
    const int wv   = tid >> 6;            // wave 0..3

    const float* xb = x + b * HH * WW * CC;

    float acc[18];
#pragma unroll
    for (int o = 0; o < 18; ++o) acc[o] = 0.f;

    for (int phase = 0; phase < 2; ++phase) {
        __syncthreads();  // previous phase readers done before overwrite
        // stage rows h-1..h+1, channels [phase*64, phase*64+64), transposed
        for (int idx = tid; idx < 3 * 64 * 64; idx += 256) {
            const int cl  = idx & 63;          // c_local (fastest -> coalesced)
            const int w   = (idx >> 6) & 63;
            const int row = idx >> 12;
            const int y   = h - 1 + row;
            float v = 0.f;
            if ((unsigned)y < (unsigned)HH)
                v = xb[(y * WW + w) * CC + phase * 64 + cl];
            smem[(row * 64 + cl) * 66 + w + 1] = v;
        }
        // zero the two padding columns (w = -1 and w = 64)
        for (int idx = tid; idx < 3 * 64 * 2; idx += 256) {
            const int row  = idx / 128;
            const int r2   = idx % 128;
            const int cl   = r2 >> 1;
            const int side = r2 & 1;
            smem[(row * 64 + cl) * 66 + (side ? 65 : 0)] = 0.f;
        }
        __syncthreads();

        // compute: this wave covers c_local in [wv*16, wv*16+16)
        for (int kh = 0; kh < 3; ++kh) {
            for (int kw = 0; kw < 3; ++kw) {
#pragma unroll 4
                for (int t = 0; t < 16; ++t) {
                    const int cl = wv * 16 + t;
                    const int c  = phase * 64 + cl;
                    const float xv = smem[(kh * 64 + cl) * 66 + lane + kw];
                    const float* wp = ow + ((kh * 3 + kw) * CC + c) * 18;  // uniform -> s_load
#pragma unroll
                    for (int o = 0; o < 18; ++o)
                        acc[o] = fmaf(xv, wp[o], acc[o]);
                }
            }
        }
    }

    __syncthreads();
    // cross-wave reduce via LDS (aliased onto smem; 4*64*18 = 4608 floats)
    float* red = smem;
#pragma unroll
    for (int o = 0; o < 18; ++o) red[(wv * 64 + lane) * 18 + o] = acc[o];
    __syncthreads();

    float* og = offs_out + (b * HH + h) * WW * 18;
    for (int i = tid; i < 64 * 18; i += 256) {
        const int px = i / 18, o = i % 18;
        og[i] = red[(0 * 64 + px) * 18 + o] + red[(1 * 64 + px) * 18 + o]
              + red[(2 * 64 + px) * 18 + o] + red[(3 * 64 + px) * 18 + o] + ob[o];
    }
}

// ---------------------------------------------------------------------------
// Kernel 2: bilinear sampling + 1152-K GEMM, fp32 vector ALU.
// grid = B*H blocks (one row: 64 px x 128 F), 256 threads.
// Per tap: fill val[64][132] in LDS (pad->33 quads, odd => 2-way read
// conflicts only), then outer-product GEMM, 4px x 8f per thread.
// Weights stream from global (L2-resident, 590 KB/block total).
// ---------------------------------------------------------------------------
__device__ __forceinline__ float4 corner_load(const float* __restrict__ xb,
                                              int yi, int xi, int c4)
{
    if ((unsigned)yi < (unsigned)HH && (unsigned)xi < (unsigned)WW)
        return *(const float4*)(xb + (yi * WW + xi) * CC + c4);
    return make_float4(0.f, 0.f, 0.f, 0.f);
}

__global__ __launch_bounds__(256, 2)
void deform_main(const float* __restrict__ x, const float* __restrict__ kern,
                 const float* __restrict__ bias, const float* __restrict__ offs_g,
                 float* __restrict__ out)
{
    __shared__ __align__(16) float val[64][132];  // [px][c], 132 floats stride
    __shared__ __align__(16) float offs[64][18];

    const int blk = blockIdx.x;  // 0..511
    const int b   = blk >> 6;
    const int h   = blk & 63;
    const int tid = threadIdx.x;

    const int pg  = tid & 15;    // GEMM: px group (px = pg + 16i)
    const int fg  = tid >> 4;    // GEMM: f group  (f  = fg*8 + j)
    const int cq  = tid & 31;    // fill: c-quad
    const int pxg = tid >> 5;    // fill: px group (px = pxg + 8*ii)

    const float* xb = x + b * HH * WW * CC;
    const float* og = offs_g + (b * HH + h) * WW * 18;
    {
        float* op = &offs[0][0];
        for (int i = tid; i < 64 * 18; i += 256) op[i] = og[i];
    }

    float acc[4][8];
    {
        const float4 blo = *(const float4*)(bias + fg * 8);
        const float4 bhi = *(const float4*)(bias + fg * 8 + 4);
#pragma unroll
        for (int i = 0; i < 4; ++i) {
            acc[i][0] = blo.x; acc[i][1] = blo.y; acc[i][2] = blo.z; acc[i][3] = blo.w;
            acc[i][4] = bhi.x; acc[i][5] = bhi.y; acc[i][6] = bhi.z; acc[i][7] = bhi.w;
        }
    }
    __syncthreads();

    for (int tap = 0; tap < 9; ++tap) {
        const int ky = tap / 3 - 1;
        const int kx = tap % 3 - 1;

        // ---- bilinear fill of val[px][c] for this tap ----
        const int c4 = cq << 2;
#pragma unroll 2
        for (int ii = 0; ii < 8; ++ii) {
            const int px = pxg + (ii << 3);
            const float dy = offs[px][2 * tap];
            const float dx = offs[px][2 * tap + 1];
            const float py  = (float)(h + ky) + dy;
            const float pxf = (float)(px + kx) + dx;
            const float y0 = floorf(py), x0 = floorf(pxf);
            const float wy = py - y0,    wx = pxf - x0;
            const int yi = (int)y0, xi = (int)x0;

            const float4 c00 = corner_load(xb, yi,     xi,     c4);
            const float4 c01 = corner_load(xb, yi,     xi + 1, c4);
            const float4 c10 = corner_load(xb, yi + 1, xi,     c4);
            const float4 c11 = corner_load(xb, yi + 1, xi + 1, c4);

            const float w00 = (1.f - wy) * (1.f - wx);
            const float w01 = (1.f - wy) * wx;
            const float w10 = wy * (1.f - wx);
            const float w11 = wy * wx;

            float4 v;
            v.x = c00.x * w00 + c01.x * w01 + c10.x * w10 + c11.x * w11;
            v.y = c00.y * w00 + c01.y * w01 + c10.y * w10 + c11.y * w11;
            v.z = c00.z * w00 + c01.z * w01 + c10.z * w10 + c11.z * w11;
            v.w = c00.w * w00 + c01.w * w01 + c10.w * w10 + c11.w * w11;
            *(float4*)&val[px][c4] = v;
        }
        __syncthreads();

        // ---- GEMM: acc[4px][8f] += val[px][c] * w[c][f] ----
        const float* wt = kern + tap * CC * FF + fg * 8;
#pragma unroll 4
        for (int cc = 0; cc < CC; cc += 4) {
            const float4 a0 = *(const float4*)&val[pg     ][cc];
            const float4 a1 = *(const float4*)&val[pg + 16][cc];
            const float4 a2 = *(const float4*)&val[pg + 32][cc];
            const float4 a3 = *(const float4*)&val[pg + 48][cc];
            const float a0a[4] = {a0.x, a0.y, a0.z, a0.w};
            const float a1a[4] = {a1.x, a1.y, a1.z, a1.w};
            const float a2a[4] = {a2.x, a2.y, a2.z, a2.w};
            const float a3a[4] = {a3.x, a3.y, a3.z, a3.w};
#pragma unroll
            for (int j = 0; j < 4; ++j) {
                const float* wr = wt + (cc + j) * FF;
                const float4 wlo = *(const float4*)(wr);
                const float4 whi = *(const float4*)(wr + 4);
                const float wa[8] = {wlo.x, wlo.y, wlo.z, wlo.w,
                                     whi.x, whi.y, whi.z, whi.w};
                const float av[4] = {a0a[j], a1a[j], a2a[j], a3a[j]};
#pragma unroll
                for (int i = 0; i < 4; ++i) {
#pragma unroll
                    for (int jf = 0; jf < 8; ++jf)
                        acc[i][jf] = fmaf(av[i], wa[jf], acc[i][jf]);
                }
            }
        }
        __syncthreads();
    }

    // ---- epilogue: store 4 px x 8 f per thread ----
    float* ob_ = out + (b * HH + h) * WW * FF + fg * 8;
#pragma unroll
    for (int i = 0; i < 4; ++i) {
        const int px = pg + (i << 4);
        float4 lo, hi;
        lo.x = acc[i][0]; lo.y = acc[i][1]; lo.z = acc[i][2]; lo.w = acc[i][3];
        hi.x = acc[i][4]; hi.y = acc[i][5]; hi.z = acc[i][6]; hi.w = acc[i][7];
        *(float4*)(ob_ + px * FF)     = lo;
        *(float4*)(ob_ + px * FF + 4) = hi;
    }
}

// ---------------------------------------------------------------------------
extern "C" void kernel_launch(void* const* d_in, const int* in_sizes, int n_in,
                              void* d_out, int out_size, void* d_ws, size_t ws_size,
                              hipStream_t stream)
{
    (void)in_sizes; (void)n_in; (void)out_size; (void)ws_size;
    const float* x    = (const float*)d_in[0];
    const float* kern = (const float*)d_in[1];
    const float* bias = (const float*)d_in[2];
    const float* ow   = (const float*)d_in[3];
    const float* ob   = (const float*)d_in[4];
    float* out  = (float*)d_out;
    float* offs = (float*)d_ws;  // B*H*W*18 fp32 = 2.25 MB scratch

    offsets_kernel<<<BB * HH, 256, 0, stream>>>(x, ow, ob, offs);
    deform_main  <<<BB * HH, 256, 0, stream>>>(x, kern, bias, offs, out);
}

// Round 6
// 260.594 us; speedup vs baseline: 1.5774x; 1.5774x over previous
//
#include <hip/hip_runtime.h>

#define BB 8
#define HH 64
#define WW 64
#define CC 128
#define FF 128

typedef __attribute__((ext_vector_type(8))) short short8v;
typedef __attribute__((ext_vector_type(4))) float float4v;

#define MFMA(a, b, c) __builtin_amdgcn_mfma_f32_16x16x32_bf16((a), (b), (c), 0, 0, 0)

__device__ __forceinline__ ushort f2bf(float f) {
    uint u = __float_as_uint(f);
    u += 0x7FFF + ((u >> 16) & 1);   // round-to-nearest-even
    return (ushort)(u >> 16);
}
__device__ __forceinline__ float bf2f(ushort h) {
    return __uint_as_float(((uint)h) << 16);
}

// workspace layout (bytes) — total 1,474,560 < 2,359,296 (round-2-proven size)
#define OFFS_BYTES (BB * HH * WW * 18 * 2)         // bf16 offsets: 1,179,648
#define NFRAG_MAIN (36 * 8 * 64)                   // 18432 B-fragments

// ---------------------------------------------------------------------------
// Kernel 0: reorder MAIN weights into MFMA B-fragment layout, bf16 (hi only —
// threshold 0.11875 gives 8x margin over plain-bf16 rounding noise).
// Fragment slot map (lane l, elem j) -> channel c0+j, c0 = (ks&3)*32+8*(l>>4),
// f = nt*16 + (l&15). A-fragments use the identical slot map.
// ---------------------------------------------------------------------------
__global__ __launch_bounds__(256)
void prep_weights(const float* __restrict__ kern, ushort* __restrict__ wfrag)
{
    int idx = blockIdx.x * 256 + threadIdx.x;
    if (idx >= NFRAG_MAIN) return;
    const int ks = idx >> 9;          // /(8*64)
    const int nt = (idx >> 6) & 7;
    const int l  = idx & 63;
    const int tap = ks >> 2;
    const int f   = nt * 16 + (l & 15);
    const int c0  = (ks & 3) * 32 + 8 * (l >> 4);
    uint p[4];
#pragma unroll
    for (int j2 = 0; j2 < 4; ++j2) {
        const ushort h0 = f2bf(kern[(tap * CC + c0 + 2 * j2) * FF + f]);
        const ushort h1 = f2bf(kern[(tap * CC + c0 + 2 * j2 + 1) * FF + f]);
        p[j2] = (uint)h0 | ((uint)h1 << 16);
    }
    *(uint4*)(wfrag + idx * 8) = make_uint4(p[0], p[1], p[2], p[3]);
}

// ---------------------------------------------------------------------------
// Kernel 1: offset conv — ROUND-2 VERIFIED fp32 kernel (bf16 final store).
// Untouched this round: held constant while the main kernel is the variable.
// ---------------------------------------------------------------------------
__global__ __launch_bounds__(256)
void offsets_kernel(const float* __restrict__ x, const float* __restrict__ ow,
                    const float* __restrict__ ob, ushort* __restrict__ offs_out)
{
    __shared__ __align__(16) float smem[3 * 64 * 66];

    const int blk  = blockIdx.x;          // 0..511
    const int b    = blk >> 6;
    const int h    = blk & 63;
    const int tid  = threadIdx.x;
    const int lane = tid & 63;            // px (column)
    const int wv   = tid >> 6;            // wave 0..3

    const float* xb = x + b * HH * WW * CC;

    float acc[18];
#pragma unroll
    for (int o = 0; o < 18; ++o) acc[o] = 0.f;

    for (int phase = 0; phase < 2; ++phase) {
        __syncthreads();
        for (int idx = tid; idx < 3 * 64 * 64; idx += 256) {
            const int cl  = idx & 63;
            const int w   = (idx >> 6) & 63;
            const int row = idx >> 12;
            const int y   = h - 1 + row;
            float v = 0.f;
            if ((unsigned)y < (unsigned)HH)
                v = xb[(y * WW + w) * CC + phase * 64 + cl];
            smem[(row * 64 + cl) * 66 + w + 1] = v;
        }
        for (int idx = tid; idx < 3 * 64 * 2; idx += 256) {
            const int row  = idx / 128;
            const int r2   = idx % 128;
            const int cl   = r2 >> 1;
            const int side = r2 & 1;
            smem[(row * 64 + cl) * 66 + (side ? 65 : 0)] = 0.f;
        }
        __syncthreads();

        for (int kh = 0; kh < 3; ++kh) {
            for (int kw = 0; kw < 3; ++kw) {
#pragma unroll 4
                for (int t = 0; t < 16; ++t) {
                    const int cl = wv * 16 + t;
                    const int c  = phase * 64 + cl;
                    const float xv = smem[(kh * 64 + cl) * 66 + lane + kw];
                    const float* wp = ow + ((kh * 3 + kw) * CC + c) * 18;
#pragma unroll
                    for (int o = 0; o < 18; ++o)
                        acc[o] = fmaf(xv, wp[o], acc[o]);
                }
            }
        }
    }

    __syncthreads();
    float* red = smem;
#pragma unroll
    for (int o = 0; o < 18; ++o) red[(wv * 64 + lane) * 18 + o] = acc[o];
    __syncthreads();

    ushort* og = offs_out + (b * HH + h) * WW * 18;
    for (int i = tid; i < 64 * 18; i += 256) {
        const int px = i / 18, o = i % 18;
        og[i] = f2bf(red[(0 * 64 + px) * 18 + o] + red[(1 * 64 + px) * 18 + o]
                   + red[(2 * 64 + px) * 18 + o] + red[(3 * 64 + px) * 18 + o] + ob[o]);
    }
}

// ---------------------------------------------------------------------------
// Kernel 2: deform conv, DIRECT-A MFMA — no LDS, no swizzle, no main-loop
// syncs. Each lane builds its own A-fragment from its bilinear corner loads:
// lane l of wave w supplies A row (l&15) (px = w*16 + (l&15)) and channels
// (ks&3)*32 + 8*(l>>4) + j — the identical slot map as the B-fragments.
// Wave w owns M-tile w (16 px) x all 128 F (8 N-tiles). bf16 hi-only.
// ---------------------------------------------------------------------------
__device__ __forceinline__ float4 corner_load(const float* __restrict__ xb,
                                              int yi, int xi, int c4)
{
    if ((unsigned)yi < (unsigned)HH && (unsigned)xi < (unsigned)WW)
        return *(const float4*)(xb + (yi * WW + xi) * CC + c4);
    return make_float4(0.f, 0.f, 0.f, 0.f);
}

__global__ __launch_bounds__(256)
void deform_direct(const float* __restrict__ x, const ushort* __restrict__ wfrag,
                   const float* __restrict__ bias, const ushort* __restrict__ offs_g,
                   float* __restrict__ out)
{
    const int bid  = blockIdx.x;
    const int swzb = (bid & 7) * 64 + (bid >> 3);   // XCD <-> image locality
    const int b = swzb >> 6, h = swzb & 63;
    const int tid = threadIdx.x, l = tid & 63, w = tid >> 6;
    const int row = l & 15, kb = l >> 4;
    const int px  = w * 16 + row;       // sampling px for THIS lane's A data

    const float* xb = x + b * HH * WW * CC;
    const ushort* og = offs_g + ((b * HH + h) * WW + px) * 18;  // 4B-aligned
    const short8v* WF = (const short8v*)wfrag;

    float4v acc[8];
#pragma unroll
    for (int nt = 0; nt < 8; ++nt) acc[nt] = (float4v){0.f, 0.f, 0.f, 0.f};

    for (int tap = 0; tap < 9; ++tap) {
        const int ky = tap / 3 - 1, kx = tap % 3 - 1;
        const uint dyx = *(const uint*)(og + 2 * tap);   // (dy, dx) bf16 pair
        const float dy = bf2f((ushort)(dyx & 0xFFFFu));
        const float dx = bf2f((ushort)(dyx >> 16));
        const float py  = (float)(h + ky) + dy;
        const float pxf = (float)(px + kx) + dx;
        const float y0f = floorf(py), x0f = floorf(pxf);
        const float wy = py - y0f, wx = pxf - x0f;
        const int yi = (int)y0f, xi = (int)x0f;
        const float w00 = (1.f - wy) * (1.f - wx);
        const float w01 = (1.f - wy) * wx;
        const float w10 = wy * (1.f - wx);
        const float w11 = wy * wx;

#pragma unroll
        for (int ks2 = 0; ks2 < 4; ++ks2) {
            const int c0 = ks2 * 32 + kb * 8;   // this lane's 8 channels
            const float4 a00 = corner_load(xb, yi,     xi,     c0);
            const float4 b00 = corner_load(xb, yi,     xi,     c0 + 4);
            const float4 a01 = corner_load(xb, yi,     xi + 1, c0);
            const float4 b01 = corner_load(xb, yi,     xi + 1, c0 + 4);
            const float4 a10 = corner_load(xb, yi + 1, xi,     c0);
            const float4 b10 = corner_load(xb, yi + 1, xi,     c0 + 4);
            const float4 a11 = corner_load(xb, yi + 1, xi + 1, c0);
            const float4 b11 = corner_load(xb, yi + 1, xi + 1, c0 + 4);

            float v[8];
            v[0] = a00.x * w00 + a01.x * w01 + a10.x * w10 + a11.x * w11;
            v[1] = a00.y * w00 + a01.y * w01 + a10.y * w10 + a11.y * w11;
            v[2] = a00.z * w00 + a01.z * w01 + a10.z * w10 + a11.z * w11;
            v[3] = a00.w * w00 + a01.w * w01 + a10.w * w10 + a11.w * w11;
            v[4] = b00.x * w00 + b01.x * w01 + b10.x * w10 + b11.x * w11;
            v[5] = b00.y * w00 + b01.y * w01 + b10.y * w10 + b11.y * w11;
            v[6] = b00.z * w00 + b01.z * w01 + b10.z * w10 + b11.z * w11;
            v[7] = b00.w * w00 + b01.w * w01 + b10.w * w10 + b11.w * w11;

            short8v ah;
#pragma unroll
            for (int j = 0; j < 8; ++j) ah[j] = (short)f2bf(v[j]);

            const int fb = ((tap * 4 + ks2) * 8) * 64 + l;
#pragma unroll
            for (int nt = 0; nt < 8; ++nt)
                acc[nt] = MFMA(ah, WF[fb + nt * 64], acc[nt]);
        }
    }

    // epilogue: C layout (m89) col = l&15 (f), row = kb*4 + r (px in tile)
    float* ob_ = out + ((b * HH + h) * WW + w * 16) * FF;
#pragma unroll
    for (int nt = 0; nt < 8; ++nt) {
        const int f = nt * 16 + (l & 15);
        const float bv = bias[f];
#pragma unroll
        for (int r = 0; r < 4; ++r) {
            const int opx = kb * 4 + r;
            ob_[opx * FF + f] = acc[nt][r] + bv;
        }
    }
}

// ---------------------------------------------------------------------------
extern "C" void kernel_launch(void* const* d_in, const int* in_sizes, int n_in,
                              void* d_out, int out_size, void* d_ws, size_t ws_size,
                              hipStream_t stream)
{
    (void)in_sizes; (void)n_in; (void)out_size; (void)ws_size;
    const float* x    = (const float*)d_in[0];
    const float* kern = (const float*)d_in[1];
    const float* bias = (const float*)d_in[2];
    const float* ow   = (const float*)d_in[3];
    const float* ob   = (const float*)d_in[4];
    float* outp = (float*)d_out;

    char* ws = (char*)d_ws;
    ushort* offs  = (ushort*)ws;                     // 1,179,648 B
    ushort* wfrag = (ushort*)(ws + OFFS_BYTES);      //   294,912 B
    // total ws usage: 1,474,560 B (< 2,359,296 proven available in round 2)

    prep_weights<<<NFRAG_MAIN / 256, 256, 0, stream>>>(kern, wfrag);
    offsets_kernel<<<BB * HH, 256, 0, stream>>>(x, ow, ob, offs);
    deform_direct<<<BB * HH, 256, 0, stream>>>(x, wfrag, bias, offs, outp);
}

// Round 7
// 179.908 us; speedup vs baseline: 2.2848x; 1.4485x over previous
//
#include <hip/hip_runtime.h>

#define BB 8
#define HH 64
#define WW 64
#define CC 128
#define FF 128

typedef __attribute__((ext_vector_type(8))) short short8v;
typedef __attribute__((ext_vector_type(4))) float float4v;

#define MFMA(a, b, c) __builtin_amdgcn_mfma_f32_16x16x32_bf16((a), (b), (c), 0, 0, 0)

__device__ __forceinline__ ushort f2bf(float f) {
    uint u = __float_as_uint(f);
    u += 0x7FFF + ((u >> 16) & 1);   // round-to-nearest-even
    return (ushort)(u >> 16);
}
__device__ __forceinline__ float bf2f(ushort h) {
    return __uint_as_float(((uint)h) << 16);
}

// workspace layout (bytes) — total 1,548,288 < 2,359,296 (round-2-proven size)
#define OFFS_BYTES (BB * HH * WW * 18 * 2)         // bf16 offsets: 1,179,648
#define NFRAG_MAIN (36 * 8 * 64)                   // 18432 main B-fragments
#define NFRAG_OFF  (36 * 2 * 64)                   // 4608 offset B-fragments

// ---------------------------------------------------------------------------
// Kernel 0: reorder weights into MFMA B-fragment layout, bf16 (hi only).
// Fragment slot map (lane l, elem j) -> channel c0+j, c0 = (ks&3)*32+8*(l>>4);
// main: f = nt*16+(l&15), nt=0..7;  offs: o = nt*16+(l&15), nt=0..1 (o>=18 -> 0).
// A-fragments are built with the IDENTICAL slot map (validated in round 6).
// ---------------------------------------------------------------------------
__global__ __launch_bounds__(256)
void prep_weights(const float* __restrict__ kern, const float* __restrict__ offw,
                  ushort* __restrict__ wfrag, ushort* __restrict__ ofrag)
{
    int idx = blockIdx.x * 256 + threadIdx.x;
    if (idx < NFRAG_MAIN) {
        const int ks = idx >> 9;          // /(8*64)
        const int nt = (idx >> 6) & 7;
        const int l  = idx & 63;
        const int tap = ks >> 2;
        const int f   = nt * 16 + (l & 15);
        const int c0  = (ks & 3) * 32 + 8 * (l >> 4);
        uint p[4];
#pragma unroll
        for (int j2 = 0; j2 < 4; ++j2) {
            const ushort h0 = f2bf(kern[(tap * CC + c0 + 2 * j2) * FF + f]);
            const ushort h1 = f2bf(kern[(tap * CC + c0 + 2 * j2 + 1) * FF + f]);
            p[j2] = (uint)h0 | ((uint)h1 << 16);
        }
        *(uint4*)(wfrag + idx * 8) = make_uint4(p[0], p[1], p[2], p[3]);
    } else if (idx < NFRAG_MAIN + NFRAG_OFF) {
        idx -= NFRAG_MAIN;
        const int ks = idx >> 7;          // /(2*64)
        const int nt = (idx >> 6) & 1;
        const int l  = idx & 63;
        const int tap = ks >> 2;
        const int o   = nt * 16 + (l & 15);
        const int c0  = (ks & 3) * 32 + 8 * (l >> 4);
        uint p[4];
#pragma unroll
        for (int j2 = 0; j2 < 4; ++j2) {
            const float v0 = (o < 18) ? offw[(tap * CC + c0 + 2 * j2) * 18 + o] : 0.f;
            const float v1 = (o < 18) ? offw[(tap * CC + c0 + 2 * j2 + 1) * 18 + o] : 0.f;
            p[j2] = (uint)f2bf(v0) | ((uint)f2bf(v1) << 16);
        }
        *(uint4*)(ofrag + idx * 8) = make_uint4(p[0], p[1], p[2], p[3]);
    }
}

// ---------------------------------------------------------------------------
// Kernel 1: offset conv as direct-A MFMA (structure validated in deform_direct).
// One block per (b,h) row, 4 waves; wave w: px = w*16 + (l&15), channels
// (ks&3)*32 + 8*(l>>4) + j. N padded 18->32 (2 N-tiles). bf16 hi-only.
// Output: bf16 offsets [B,H,W,18] in workspace.
// ---------------------------------------------------------------------------
__global__ __launch_bounds__(256)
void offsets_mfma(const float* __restrict__ x, const ushort* __restrict__ ofrag,
                  const float* __restrict__ ob, ushort* __restrict__ offs_out)
{
    const int bid  = blockIdx.x;
    const int swzb = (bid & 7) * 64 + (bid >> 3);   // XCD <-> image locality
    const int b = swzb >> 6, h = swzb & 63;
    const int tid = threadIdx.x, l = tid & 63, w = tid >> 6;
    const int row = l & 15, kb = l >> 4;
    const int px  = w * 16 + row;

    const float* xb = x + b * HH * WW * CC;
    const short8v* OF = (const short8v*)ofrag;

    float4v acc0 = {0.f, 0.f, 0.f, 0.f};
    float4v acc1 = {0.f, 0.f, 0.f, 0.f};

    for (int ks = 0; ks < 36; ++ks) {
        const int tap = ks >> 2;
        const int ky = tap / 3 - 1, kx = tap % 3 - 1;
        const int y = h + ky;
        if ((unsigned)y >= (unsigned)HH) continue;   // block-uniform branch
        const int xc = px + kx;
        const int c0 = (ks & 3) * 32 + kb * 8;

        float4 v0 = make_float4(0.f, 0.f, 0.f, 0.f);
        float4 v1 = make_float4(0.f, 0.f, 0.f, 0.f);
        if ((unsigned)xc < (unsigned)WW) {
            const float* p = xb + (y * WW + xc) * CC + c0;
            v0 = *(const float4*)p;
            v1 = *(const float4*)(p + 4);
        }
        short8v ah;
        ah[0] = (short)f2bf(v0.x); ah[1] = (short)f2bf(v0.y);
        ah[2] = (short)f2bf(v0.z); ah[3] = (short)f2bf(v0.w);
        ah[4] = (short)f2bf(v1.x); ah[5] = (short)f2bf(v1.y);
        ah[6] = (short)f2bf(v1.z); ah[7] = (short)f2bf(v1.w);

        acc0 = MFMA(ah, OF[(ks * 2 + 0) * 64 + l], acc0);
        acc1 = MFMA(ah, OF[(ks * 2 + 1) * 64 + l], acc1);
    }

    // C layout (validated): col = l&15, row = kb*4 + r (px within wave tile)
    ushort* og = offs_out + (b * HH + h) * WW * 18;
#pragma unroll
    for (int nt = 0; nt < 2; ++nt) {
        const int o = nt * 16 + (l & 15);
        if (o < 18) {
            const float bo = ob[o];
            const float4v a = nt ? acc1 : acc0;
#pragma unroll
            for (int r = 0; r < 4; ++r) {
                const int ppx = w * 16 + kb * 4 + r;
                og[ppx * 18 + o] = f2bf(a[r] + bo);
            }
        }
    }
}

// ---------------------------------------------------------------------------
// Kernel 2: deform conv, DIRECT-A MFMA (round-6 validated, FROZEN this round).
// ---------------------------------------------------------------------------
__device__ __forceinline__ float4 corner_load(const float* __restrict__ xb,
                                              int yi, int xi, int c4)
{
    if ((unsigned)yi < (unsigned)HH && (unsigned)xi < (unsigned)WW)
        return *(const float4*)(xb + (yi * WW + xi) * CC + c4);
    return make_float4(0.f, 0.f, 0.f, 0.f);
}

__global__ __launch_bounds__(256)
void deform_direct(const float* __restrict__ x, const ushort* __restrict__ wfrag,
                   const float* __restrict__ bias, const ushort* __restrict__ offs_g,
                   float* __restrict__ out)
{
    const int bid  = blockIdx.x;
    const int swzb = (bid & 7) * 64 + (bid >> 3);   // XCD <-> image locality
    const int b = swzb >> 6, h = swzb & 63;
    const int tid = threadIdx.x, l = tid & 63, w = tid >> 6;
    const int row = l & 15, kb = l >> 4;
    const int px  = w * 16 + row;       // sampling px for THIS lane's A data

    const float* xb = x + b * HH * WW * CC;
    const ushort* og = offs_g + ((b * HH + h) * WW + px) * 18;  // 4B-aligned
    const short8v* WF = (const short8v*)wfrag;

    float4v acc[8];
#pragma unroll
    for (int nt = 0; nt < 8; ++nt) acc[nt] = (float4v){0.f, 0.f, 0.f, 0.f};

    for (int tap = 0; tap < 9; ++tap) {
        const int ky = tap / 3 - 1, kx = tap % 3 - 1;
        const uint dyx = *(const uint*)(og + 2 * tap);   // (dy, dx) bf16 pair
        const float dy = bf2f((ushort)(dyx & 0xFFFFu));
        const float dx = bf2f((ushort)(dyx >> 16));
        const float py  = (float)(h + ky) + dy;
        const float pxf = (float)(px + kx) + dx;
        const float y0f = floorf(py), x0f = floorf(pxf);
        const float wy = py - y0f, wx = pxf - x0f;
        const int yi = (int)y0f, xi = (int)x0f;
        const float w00 = (1.f - wy) * (1.f - wx);
        const float w01 = (1.f - wy) * wx;
        const float w10 = wy * (1.f - wx);
        const float w11 = wy * wx;

#pragma unroll
        for (int ks2 = 0; ks2 < 4; ++ks2) {
            const int c0 = ks2 * 32 + kb * 8;   // this lane's 8 channels
            const float4 a00 = corner_load(xb, yi,     xi,     c0);
            const float4 b00 = corner_load(xb, yi,     xi,     c0 + 4);
            const float4 a01 = corner_load(xb, yi,     xi + 1, c0);
            const float4 b01 = corner_load(xb, yi,     xi + 1, c0 + 4);
            const float4 a10 = corner_load(xb, yi + 1, xi,     c0);
            const float4 b10 = corner_load(xb, yi + 1, xi,     c0 + 4);
            const float4 a11 = corner_load(xb, yi + 1, xi + 1, c0);
            const float4 b11 = corner_load(xb, yi + 1, xi + 1, c0 + 4);

            float v[8];
            v[0] = a00.x * w00 + a01.x * w01 + a10.x * w10 + a11.x * w11;
            v[1] = a00.y * w00 + a01.y * w01 + a10.y * w10 + a11.y * w11;
            v[2] = a00.z * w00 + a01.z * w01 + a10.z * w10 + a11.z * w11;
            v[3] = a00.w * w00 + a01.w * w01 + a10.w * w10 + a11.w * w11;
            v[4] = b00.x * w00 + b01.x * w01 + b10.x * w10 + b11.x * w11;
            v[5] = b00.y * w00 + b01.y * w01 + b10.y * w10 + b11.y * w11;
            v[6] = b00.z * w00 + b01.z * w01 + b10.z * w10 + b11.z * w11;
            v[7] = b00.w * w00 + b01.w * w01 + b10.w * w10 + b11.w * w11;

            short8v ah;
#pragma unroll
            for (int j = 0; j < 8; ++j) ah[j] = (short)f2bf(v[j]);

            const int fb = ((tap * 4 + ks2) * 8) * 64 + l;
#pragma unroll
            for (int nt = 0; nt < 8; ++nt)
                acc[nt] = MFMA(ah, WF[fb + nt * 64], acc[nt]);
        }
    }

    // epilogue: C layout (validated) col = l&15 (f), row = kb*4 + r (px in tile)
    float* ob_ = out + ((b * HH + h) * WW + w * 16) * FF;
#pragma unroll
    for (int nt = 0; nt < 8; ++nt) {
        const int f = nt * 16 + (l & 15);
        const float bv = bias[f];
#pragma unroll
        for (int r = 0; r < 4; ++r) {
            const int opx = kb * 4 + r;
            ob_[opx * FF + f] = acc[nt][r] + bv;
        }
    }
}

// ---------------------------------------------------------------------------
extern "C" void kernel_launch(void* const* d_in, const int* in_sizes, int n_in,
                              void* d_out, int out_size, void* d_ws, size_t ws_size,
                              hipStream_t stream)
{
    (void)in_sizes; (void)n_in; (void)out_size; (void)ws_size;
    const float* x    = (const float*)d_in[0];
    const float* kern = (const float*)d_in[1];
    const float* bias = (const float*)d_in[2];
    const float* ow   = (const float*)d_in[3];
    const float* ob   = (const float*)d_in[4];
    float* outp = (float*)d_out;

    char* ws = (char*)d_ws;
    ushort* offs  = (ushort*)ws;                              // 1,179,648 B
    ushort* wfrag = (ushort*)(ws + OFFS_BYTES);               //   294,912 B
    ushort* ofrag = (ushort*)(ws + OFFS_BYTES + 294912);      //    73,728 B
    // total ws usage: 1,548,288 B (< 2,359,296 proven available in round 2)

    const int prep_threads = NFRAG_MAIN + NFRAG_OFF;          // 23040
    prep_weights<<<(prep_threads + 255) / 256, 256, 0, stream>>>(kern, ow, wfrag, ofrag);
    offsets_mfma<<<BB * HH, 256, 0, stream>>>(x, ofrag, ob, offs);
    deform_direct<<<BB * HH, 256, 0, stream>>>(x, wfrag, bias, offs, outp);
}

// Round 9
// 174.710 us; speedup vs baseline: 2.3528x; 1.0298x over previous
//
#include <hip/hip_runtime.h>

#define BB 8
#define HH 64
#define WW 64
#define CC 128
#define FF 128

typedef __attribute__((ext_vector_type(8))) short short8v;
typedef __attribute__((ext_vector_type(4))) float float4v;

#define MFMA(a, b, c) __builtin_amdgcn_mfma_f32_16x16x32_bf16((a), (b), (c), 0, 0, 0)

__device__ __forceinline__ ushort f2bf(float f) {
    uint u = __float_as_uint(f);
    u += 0x7FFF + ((u >> 16) & 1);   // round-to-nearest-even
    return (ushort)(u >> 16);
}
__device__ __forceinline__ float bf2f(ushort h) {
    return __uint_as_float(((uint)h) << 16);
}

// workspace layout (bytes) — total 1,548,288 < 2,359,296 (round-2-proven size)
#define OFFS_BYTES (BB * HH * WW * 18 * 2)         // bf16 offsets: 1,179,648
#define NFRAG_MAIN (36 * 8 * 64)                   // 18432 main B-fragments
#define NFRAG_OFF  (36 * 2 * 64)                   // 4608 offset B-fragments

// ---------------------------------------------------------------------------
// Kernel 0: reorder weights into MFMA B-fragment layout, bf16 (FROZEN).
// ---------------------------------------------------------------------------
__global__ __launch_bounds__(256)
void prep_weights(const float* __restrict__ kern, const float* __restrict__ offw,
                  ushort* __restrict__ wfrag, ushort* __restrict__ ofrag)
{
    int idx = blockIdx.x * 256 + threadIdx.x;
    if (idx < NFRAG_MAIN) {
        const int ks = idx >> 9;          // /(8*64)
        const int nt = (idx >> 6) & 7;
        const int l  = idx & 63;
        const int tap = ks >> 2;
        const int f   = nt * 16 + (l & 15);
        const int c0  = (ks & 3) * 32 + 8 * (l >> 4);
        uint p[4];
#pragma unroll
        for (int j2 = 0; j2 < 4; ++j2) {
            const ushort h0 = f2bf(kern[(tap * CC + c0 + 2 * j2) * FF + f]);
            const ushort h1 = f2bf(kern[(tap * CC + c0 + 2 * j2 + 1) * FF + f]);
            p[j2] = (uint)h0 | ((uint)h1 << 16);
        }
        *(uint4*)(wfrag + idx * 8) = make_uint4(p[0], p[1], p[2], p[3]);
    } else if (idx < NFRAG_MAIN + NFRAG_OFF) {
        idx -= NFRAG_MAIN;
        const int ks = idx >> 7;          // /(2*64)
        const int nt = (idx >> 6) & 1;
        const int l  = idx & 63;
        const int tap = ks >> 2;
        const int o   = nt * 16 + (l & 15);
        const int c0  = (ks & 3) * 32 + 8 * (l >> 4);
        uint p[4];
#pragma unroll
        for (int j2 = 0; j2 < 4; ++j2) {
            const float v0 = (o < 18) ? offw[(tap * CC + c0 + 2 * j2) * 18 + o] : 0.f;
            const float v1 = (o < 18) ? offw[(tap * CC + c0 + 2 * j2 + 1) * 18 + o] : 0.f;
            p[j2] = (uint)f2bf(v0) | ((uint)f2bf(v1) << 16);
        }
        *(uint4*)(ofrag + idx * 8) = make_uint4(p[0], p[1], p[2], p[3]);
    }
}

// ---------------------------------------------------------------------------
// Kernel 1: offset conv, direct-A MFMA (FROZEN — round-7 validated).
// ---------------------------------------------------------------------------
__global__ __launch_bounds__(256)
void offsets_mfma(const float* __restrict__ x, const ushort* __restrict__ ofrag,
                  const float* __restrict__ ob, ushort* __restrict__ offs_out)
{
    const int bid  = blockIdx.x;
    const int swzb = (bid & 7) * 64 + (bid >> 3);   // XCD <-> image locality
    const int b = swzb >> 6, h = swzb & 63;
    const int tid = threadIdx.x, l = tid & 63, w = tid >> 6;
    const int row = l & 15, kb = l >> 4;
    const int px  = w * 16 + row;

    const float* xb = x + b * HH * WW * CC;
    const short8v* OF = (const short8v*)ofrag;

    float4v acc0 = {0.f, 0.f, 0.f, 0.f};
    float4v acc1 = {0.f, 0.f, 0.f, 0.f};

    for (int ks = 0; ks < 36; ++ks) {
        const int tap = ks >> 2;
        const int ky = tap / 3 - 1, kx = tap % 3 - 1;
        const int y = h + ky;
        if ((unsigned)y >= (unsigned)HH) continue;   // block-uniform branch
        const int xc = px + kx;
        const int c0 = (ks & 3) * 32 + kb * 8;

        float4 v0 = make_float4(0.f, 0.f, 0.f, 0.f);
        float4 v1 = make_float4(0.f, 0.f, 0.f, 0.f);
        if ((unsigned)xc < (unsigned)WW) {
            const float* p = xb + (y * WW + xc) * CC + c0;
            v0 = *(const float4*)p;
            v1 = *(const float4*)(p + 4);
        }
        short8v ah;
        ah[0] = (short)f2bf(v0.x); ah[1] = (short)f2bf(v0.y);
        ah[2] = (short)f2bf(v0.z); ah[3] = (short)f2bf(v0.w);
        ah[4] = (short)f2bf(v1.x); ah[5] = (short)f2bf(v1.y);
        ah[6] = (short)f2bf(v1.z); ah[7] = (short)f2bf(v1.w);

        acc0 = MFMA(ah, OF[(ks * 2 + 0) * 64 + l], acc0);
        acc1 = MFMA(ah, OF[(ks * 2 + 1) * 64 + l], acc1);
    }

    ushort* og = offs_out + (b * HH + h) * WW * 18;
#pragma unroll
    for (int nt = 0; nt < 2; ++nt) {
        const int o = nt * 16 + (l & 15);
        if (o < 18) {
            const float bo = ob[o];
            const float4v a = nt ? acc1 : acc0;
#pragma unroll
            for (int r = 0; r < 4; ++r) {
                const int ppx = w * 16 + kb * 4 + r;
                og[ppx * 18 + o] = f2bf(a[r] + bo);
            }
        }
    }
}

// ---------------------------------------------------------------------------
// Kernel 2: deform conv, direct-A MFMA + K-SPLIT x2.
// 8 waves/block: waves 0-3 (group 0) accumulate taps 0-3, waves 4-7 (group 1)
// taps 4-8, over the same 16px x 128F tiles. Group 1 spills fp32 partials to
// LDS; one uniform barrier; group 0 adds + bias + stores. Halves each wave's
// serial load chain and doubles occupancy to 4 waves/SIMD (launch_bounds cap).
// ---------------------------------------------------------------------------
__device__ __forceinline__ float4 corner_load(const float* __restrict__ xb,
                                              int yi, int xi, int c4)
{
    if ((unsigned)yi < (unsigned)HH && (unsigned)xi < (unsigned)WW)
        return *(const float4*)(xb + (yi * WW + xi) * CC + c4);
    return make_float4(0.f, 0.f, 0.f, 0.f);
}

__global__ __launch_bounds__(512, 4)
void deform_direct(const float* __restrict__ x, const ushort* __restrict__ wfrag,
                   const float* __restrict__ bias, const ushort* __restrict__ offs_g,
                   float* __restrict__ out)
{
    __shared__ float4 lds_red[8 * 4 * 64];   // [nt][pxtile][lane], 32 KB

    const int bid  = blockIdx.x;
    const int swzb = (bid & 7) * 64 + (bid >> 3);   // XCD <-> image locality
    const int b = swzb >> 6, h = swzb & 63;
    const int tid = threadIdx.x, l = tid & 63, wv = tid >> 6;
    const int g = wv >> 2;              // tap group: 0 -> taps 0-3, 1 -> taps 4-8
    const int t = wv & 3;               // px tile
    const int row = l & 15, kb = l >> 4;
    const int px  = t * 16 + row;       // sampling px for THIS lane's A data

    const float* xb = x + b * HH * WW * CC;
    const ushort* og = offs_g + ((b * HH + h) * WW + px) * 18;  // 4B-aligned
    const short8v* WF = (const short8v*)wfrag;

    float4v acc[8];
#pragma unroll
    for (int nt = 0; nt < 8; ++nt) acc[nt] = (float4v){0.f, 0.f, 0.f, 0.f};

    const int tap_begin = g ? 4 : 0;
    const int tap_end   = g ? 9 : 4;

    uint dyx_next = *(const uint*)(og + 2 * tap_begin);
#pragma unroll 1
    for (int tap = tap_begin; tap < tap_end; ++tap) {
        const uint dyx = dyx_next;
        if (tap + 1 < tap_end) dyx_next = *(const uint*)(og + 2 * (tap + 1));

        const int ky = tap / 3 - 1, kx = tap % 3 - 1;
        const float dy = bf2f((ushort)(dyx & 0xFFFFu));
        const float dx = bf2f((ushort)(dyx >> 16));
        const float py  = (float)(h + ky) + dy;
        const float pxf = (float)(px + kx) + dx;
        const float y0f = floorf(py), x0f = floorf(pxf);
        const float wy = py - y0f, wx = pxf - x0f;
        const int yi = (int)y0f, xi = (int)x0f;
        const float w00 = (1.f - wy) * (1.f - wx);
        const float w01 = (1.f - wy) * wx;
        const float w10 = wy * (1.f - wx);
        const float w11 = wy * wx;

#pragma unroll
        for (int ks2 = 0; ks2 < 4; ++ks2) {
            const int c0 = ks2 * 32 + kb * 8;   // this lane's 8 channels
            const float4 a00 = corner_load(xb, yi,     xi,     c0);
            const float4 b00 = corner_load(xb, yi,     xi,     c0 + 4);
            const float4 a01 = corner_load(xb, yi,     xi + 1, c0);
            const float4 b01 = corner_load(xb, yi,     xi + 1, c0 + 4);
            const float4 a10 = corner_load(xb, yi + 1, xi,     c0);
            const float4 b10 = corner_load(xb, yi + 1, xi,     c0 + 4);
            const float4 a11 = corner_load(xb, yi + 1, xi + 1, c0);
            const float4 b11 = corner_load(xb, yi + 1, xi + 1, c0 + 4);

            float v[8];
            v[0] = a00.x * w00 + a01.x * w01 + a10.x * w10 + a11.x * w11;
            v[1] = a00.y * w00 + a01.y * w01 + a10.y * w10 + a11.y * w11;
            v[2] = a00.z * w00 + a01.z * w01 + a10.z * w10 + a11.z * w11;
            v[3] = a00.w * w00 + a01.w * w01 + a10.w * w10 + a11.w * w11;
            v[4] = b00.x * w00 + b01.x * w01 + b10.x * w10 + b11.x * w11;
            v[5] = b00.y * w00 + b01.y * w01 + b10.y * w10 + b11.y * w11;
            v[6] = b00.z * w00 + b01.z * w01 + b10.z * w10 + b11.z * w11;
            v[7] = b00.w * w00 + b01.w * w01 + b10.w * w10 + b11.w * w11;

            short8v ah;
#pragma unroll
            for (int j = 0; j < 8; ++j) ah[j] = (short)f2bf(v[j]);

            const int fb = ((tap * 4 + ks2) * 8) * 64 + l;
#pragma unroll
            for (int nt = 0; nt < 8; ++nt)
                acc[nt] = MFMA(ah, WF[fb + nt * 64], acc[nt]);
        }
    }

    // ---- K-split reduction: group 1 -> LDS, barrier, group 0 adds+stores ----
    if (g == 1) {
#pragma unroll
        for (int nt = 0; nt < 8; ++nt)
            lds_red[(nt * 4 + t) * 64 + l] =
                make_float4(acc[nt][0], acc[nt][1], acc[nt][2], acc[nt][3]);
    }
    __syncthreads();
    if (g == 0) {
        // epilogue: C layout (validated) col = l&15 (f), row = kb*4 + r (px)
        float* ob_ = out + ((b * HH + h) * WW + t * 16) * FF;
#pragma unroll
        for (int nt = 0; nt < 8; ++nt) {
            const int f = nt * 16 + (l & 15);
            const float bv = bias[f];
            const float4 p = lds_red[(nt * 4 + t) * 64 + l];
            const float pr[4] = {p.x, p.y, p.z, p.w};
#pragma unroll
            for (int r = 0; r < 4; ++r) {
                const int opx = kb * 4 + r;
                ob_[opx * FF + f] = acc[nt][r] + pr[r] + bv;
            }
        }
    }
}

// ---------------------------------------------------------------------------
extern "C" void kernel_launch(void* const* d_in, const int* in_sizes, int n_in,
                              void* d_out, int out_size, void* d_ws, size_t ws_size,
                              hipStream_t stream)
{
    (void)in_sizes; (void)n_in; (void)out_size; (void)ws_size;
    const float* x    = (const float*)d_in[0];
    const float* kern = (const float*)d_in[1];
    const float* bias = (const float*)d_in[2];
    const float* ow   = (const float*)d_in[3];
    const float* ob   = (const float*)d_in[4];
    float* outp = (float*)d_out;

    char* ws = (char*)d_ws;
    ushort* offs  = (ushort*)ws;                              // 1,179,648 B
    ushort* wfrag = (ushort*)(ws + OFFS_BYTES);               //   294,912 B
    ushort* ofrag = (ushort*)(ws + OFFS_BYTES + 294912);      //    73,728 B
    // total ws usage: 1,548,288 B (< 2,359,296 proven available in round 2)

    const int prep_threads = NFRAG_MAIN + NFRAG_OFF;          // 23040
    prep_weights<<<(prep_threads + 255) / 256, 256, 0, stream>>>(kern, ow, wfrag, ofrag);
    offsets_mfma<<<BB * HH, 256, 0, stream>>>(x, ofrag, ob, offs);
    deform_direct<<<BB * HH, 512, 0, stream>>>(x, wfrag, bias, offs, outp);
}